// Round 1
// baseline (661.736 us; speedup 1.0000x reference)
//
#include <hip/hip_runtime.h>

typedef unsigned short u16;
typedef __attribute__((ext_vector_type(4))) float floatx4;
typedef __attribute__((ext_vector_type(8))) short shortx8;

__device__ __constant__ float NF4C[16] = {
    -1.0f, -0.6962f, -0.5251f, -0.3949f, -0.2844f, -0.1848f, -0.0911f, 0.0f,
     0.0796f, 0.1609f, 0.2461f, 0.3379f, 0.4407f, 0.5626f, 0.723f, 1.0f};

__device__ __forceinline__ unsigned f2bf(float f) {
    unsigned u = __float_as_uint(f);
    return (u + 0x7FFFu + ((u >> 16) & 1u)) >> 16;   // RNE
}

__device__ __forceinline__ void ld_lds16(const u16* g, u16* l) {
    __builtin_amdgcn_global_load_lds(
        (const __attribute__((address_space(1))) void*)g,
        (__attribute__((address_space(3))) void*)l,
        16, 0, 0);
}

// ---------------- preprocessing ----------------

__global__ __launch_bounds__(256) void cvt_x(const float* __restrict__ x,
                                             u16* __restrict__ xb) {
    const size_t i = ((size_t)blockIdx.x * 256 + threadIdx.x) * 8;
    float4 f0 = *(const float4*)(x + i);
    float4 f1 = *(const float4*)(x + i + 4);
    uint4 o;
    o.x = f2bf(f0.x) | (f2bf(f0.y) << 16);
    o.y = f2bf(f0.z) | (f2bf(f0.w) << 16);
    o.z = f2bf(f1.x) | (f2bf(f1.y) << 16);
    o.w = f2bf(f1.z) | (f2bf(f1.w) << 16);
    *(uint4*)(xb + i) = o;
}

__global__ __launch_bounds__(256) void deq_w(const int* __restrict__ qi,
                                             const float* __restrict__ sc,
                                             u16* __restrict__ wb) {
    const size_t i = ((size_t)blockIdx.x * 256 + threadIdx.x) * 8;
    const float s = sc[i >> 10];          // 8 consecutive elems share one 1024-block
    int4 q0 = *(const int4*)(qi + i);
    int4 q1 = *(const int4*)(qi + i + 4);
    uint4 o;
    o.x = f2bf(NF4C[q0.x] * s) | (f2bf(NF4C[q0.y] * s) << 16);
    o.y = f2bf(NF4C[q0.z] * s) | (f2bf(NF4C[q0.w] * s) << 16);
    o.z = f2bf(NF4C[q1.x] * s) | (f2bf(NF4C[q1.y] * s) << 16);
    o.w = f2bf(NF4C[q1.z] * s) | (f2bf(NF4C[q1.w] * s) << 16);
    *(uint4*)(wb + i) = o;
}

// ---------------- main GEMM (m97 structure: 128x128 tile, BK=32) ----------------
// A: [M,K] bf16 row-major (x), B: [N,K] bf16 row-major (W) -> C = A*B^T, fp32 [M,N]

#define BM 128
#define BN 128
#define BK 32

__global__ __launch_bounds__(256) void gemm_bt(const u16* __restrict__ A,
                                               const u16* __restrict__ B,
                                               float* __restrict__ C) {
    constexpr int K = 4096, N = 4096;
    __shared__ __align__(16) u16 As[BM * BK];   // 8 KiB
    __shared__ __align__(16) u16 Bs[BN * BK];   // 8 KiB

    const int t    = threadIdx.x;
    const int wave = t >> 6;
    const int lane = t & 63;
    const int quad = lane >> 4;
    const int r16  = lane & 15;
    const int bm   = blockIdx.y * BM;
    const int bn   = blockIdx.x * BN;

    // staging: thread t loads 8 bf16; tile elem offset e = t*8 (inst0), +2048 (inst1)
    const int e    = t * 8;
    const int srow = e >> 5;           // 0..63
    const int scol = e & 31;
    const u16* ga = A + (size_t)(bm + srow) * K + scol;
    const u16* gb = B + (size_t)(bn + srow) * K + scol;
    u16* la = &As[wave * 512];         // wave-uniform LDS dest (lane scatter is HW-implicit)
    u16* lb = &Bs[wave * 512];

    const int wm = (wave >> 1) * 64;   // 2x2 waves -> 64x64 per wave
    const int wn = (wave & 1) * 64;

    floatx4 acc[4][4];
#pragma unroll
    for (int i = 0; i < 4; i++)
#pragma unroll
        for (int j = 0; j < 4; j++) acc[i][j] = (floatx4)0.0f;

    for (int kt = 0; kt < K / BK; ++kt) {
        ld_lds16(ga, la);
        ld_lds16(ga + 64 * K, la + 2048);
        ld_lds16(gb, lb);
        ld_lds16(gb + 64 * K, lb + 2048);
        ga += BK;
        gb += BK;
        __syncthreads();   // drains vmcnt -> LDS tiles complete

        shortx8 af[4], bf[4];
#pragma unroll
        for (int i = 0; i < 4; i++)
            af[i] = *(const shortx8*)&As[(wm + i * 16 + r16) * BK + quad * 8];
#pragma unroll
        for (int j = 0; j < 4; j++)
            bf[j] = *(const shortx8*)&Bs[(wn + j * 16 + r16) * BK + quad * 8];

#pragma unroll
        for (int i = 0; i < 4; i++)
#pragma unroll
            for (int j = 0; j < 4; j++)
                acc[i][j] = __builtin_amdgcn_mfma_f32_16x16x32_bf16(
                    af[i], bf[j], acc[i][j], 0, 0, 0);
        __syncthreads();   // protect LDS before next stage
    }

    // epilogue: C/D layout col=lane&15, row=quad*4+reg  [verified m89]
#pragma unroll
    for (int i = 0; i < 4; i++) {
#pragma unroll
        for (int j = 0; j < 4; j++) {
            const int row0 = bm + wm + i * 16 + quad * 4;
            const int col  = bn + wn + j * 16 + r16;
#pragma unroll
            for (int v = 0; v < 4; ++v)
                C[(size_t)(row0 + v) * N + col] = acc[i][j][v];
        }
    }
}

// ---------------- fallback (ws too small): fp32 tiled, dequant on the fly ----------------

__global__ __launch_bounds__(256) void fallback_gemm(const float* __restrict__ x,
                                                     const int* __restrict__ qi,
                                                     const float* __restrict__ sc,
                                                     float* __restrict__ y) {
    __shared__ float xs[16][16];
    __shared__ float wsm[16][17];
    const int tx = threadIdx.x, ty = threadIdx.y;
    const int m = blockIdx.y * 16 + ty;
    const int nrow = blockIdx.x * 16 + ty;   // W row loaded by this thread
    float acc = 0.f;
    for (int k0 = 0; k0 < 4096; k0 += 16) {
        xs[ty][tx] = x[(size_t)m * 4096 + k0 + tx];
        const size_t fi = (size_t)nrow * 4096 + k0 + tx;
        wsm[ty][tx] = NF4C[qi[fi]] * sc[fi >> 10];
        __syncthreads();
#pragma unroll
        for (int kk = 0; kk < 16; kk++) acc += xs[ty][kk] * wsm[tx][kk];
        __syncthreads();
    }
    y[(size_t)m * 4096 + blockIdx.x * 16 + tx] = acc;
}

// ---------------- launch ----------------

extern "C" void kernel_launch(void* const* d_in, const int* in_sizes, int n_in,
                              void* d_out, int out_size, void* d_ws, size_t ws_size,
                              hipStream_t stream) {
    const float* x  = (const float*)d_in[0];
    const int*   qi = (const int*)d_in[1];
    const float* sc = (const float*)d_in[2];
    float* y = (float*)d_out;

    const int M = 8192, N = 4096, K = 4096;
    const size_t xb_bytes = (size_t)M * K * 2;   // 64 MiB
    const size_t wb_bytes = (size_t)N * K * 2;   // 32 MiB

    if (ws_size >= xb_bytes + wb_bytes) {
        u16* xb = (u16*)d_ws;
        u16* wb = (u16*)((char*)d_ws + xb_bytes);
        cvt_x<<<(M * K) / (256 * 8), 256, 0, stream>>>(x, xb);
        deq_w<<<(N * K) / (256 * 8), 256, 0, stream>>>(qi, sc, wb);
        dim3 grid(N / BN, M / BM);   // (32, 64)
        gemm_bt<<<grid, 256, 0, stream>>>(xb, wb, y);
    } else {
        dim3 block(16, 16);
        dim3 grid(N / 16, M / 16);
        fallback_gemm<<<grid, block, 0, stream>>>(x, qi, sc, y);
    }
}

// Round 2
// 618.799 us; speedup vs baseline: 1.0694x; 1.0694x over previous
//
#include <hip/hip_runtime.h>

typedef unsigned short u16;
typedef __attribute__((ext_vector_type(4))) float  f32x4;
typedef __attribute__((ext_vector_type(4))) int    i32x4;
typedef __attribute__((ext_vector_type(4))) unsigned u32x4;
typedef __attribute__((ext_vector_type(8))) short  shortx8;

__device__ __constant__ float NF4C[16] = {
    -1.0f, -0.6962f, -0.5251f, -0.3949f, -0.2844f, -0.1848f, -0.0911f, 0.0f,
     0.0796f, 0.1609f, 0.2461f, 0.3379f, 0.4407f, 0.5626f, 0.723f, 1.0f};

__device__ __forceinline__ unsigned f2bf(float f) {
    unsigned u = __float_as_uint(f);
    return (u + 0x7FFFu + ((u >> 16) & 1u)) >> 16;   // RNE
}

__device__ __forceinline__ void ld_lds16(const u16* g, u16* l) {
    __builtin_amdgcn_global_load_lds(
        (const __attribute__((address_space(1))) void*)g,
        (__attribute__((address_space(3))) void*)l,
        16, 0, 0);
}

// ---------------- preprocessing ----------------

__global__ __launch_bounds__(256) void cvt_x(const float* __restrict__ x,
                                             u16* __restrict__ xb) {
    const size_t i = ((size_t)blockIdx.x * 256 + threadIdx.x) * 8;
    f32x4 f0 = __builtin_nontemporal_load((const f32x4*)(x + i));      // read-once
    f32x4 f1 = __builtin_nontemporal_load((const f32x4*)(x + i + 4));
    u32x4 o;
    o[0] = f2bf(f0[0]) | (f2bf(f0[1]) << 16);
    o[1] = f2bf(f0[2]) | (f2bf(f0[3]) << 16);
    o[2] = f2bf(f1[0]) | (f2bf(f1[1]) << 16);
    o[3] = f2bf(f1[2]) | (f2bf(f1[3]) << 16);
    *(u32x4*)(xb + i) = o;   // cached: GEMM re-reads from L2/L3
}

__global__ __launch_bounds__(256) void deq_w(const int* __restrict__ qi,
                                             const float* __restrict__ sc,
                                             u16* __restrict__ wb) {
    const size_t i = ((size_t)blockIdx.x * 256 + threadIdx.x) * 8;
    const float s = sc[i >> 10];          // 8 consecutive elems share one 1024-block
    i32x4 q0 = __builtin_nontemporal_load((const i32x4*)(qi + i));     // read-once
    i32x4 q1 = __builtin_nontemporal_load((const i32x4*)(qi + i + 4));
    u32x4 o;
    o[0] = f2bf(NF4C[q0[0]] * s) | (f2bf(NF4C[q0[1]] * s) << 16);
    o[1] = f2bf(NF4C[q0[2]] * s) | (f2bf(NF4C[q0[3]] * s) << 16);
    o[2] = f2bf(NF4C[q1[0]] * s) | (f2bf(NF4C[q1[1]] * s) << 16);
    o[3] = f2bf(NF4C[q1[2]] * s) | (f2bf(NF4C[q1[3]] * s) << 16);
    *(u32x4*)(wb + i) = o;
}

// ---------------- main GEMM (m97 structure + XOR bank swizzle) ----------------
// A: [M,K] bf16 row-major (x), B: [N,K] bf16 row-major (W) -> C = A*B^T, fp32 [M,N]
//
// LDS layout: 16B chunk at slot (row, c) holds global chunk (row, c ^ k(row)),
// k(row) = (row>>1)&3. Staging: lane t fetches chunk (t&3)^((t>>3)&3) of its
// row (same 64B line per 4-lane group -> coalescing unchanged; DMA lane->slot
// mapping fixed). Read bank = (16*r16 + 4*(quad^((r16>>1)&3))) mod 32 -> exactly
// 2 lanes/bank = free (m136).

#define BM 128
#define BN 128
#define BK 32

__global__ __launch_bounds__(256) void gemm_bt(const u16* __restrict__ A,
                                               const u16* __restrict__ B,
                                               float* __restrict__ C) {
    constexpr int K = 4096, N = 4096;
    __shared__ __align__(16) u16 As[BM * BK];   // 8 KiB
    __shared__ __align__(16) u16 Bs[BN * BK];   // 8 KiB

    const int t    = threadIdx.x;
    const int wave = t >> 6;
    const int lane = t & 63;
    const int quad = lane >> 4;
    const int r16  = lane & 15;

    // XCD-aware supertile swizzle (MI355X round-robins block id % 8 across XCDs):
    // each XCD gets an 8(M)x32(N) block region, walked in 8-row x 4-col strips.
    const int id     = blockIdx.x;       // 0..2047
    const int xcd    = id & 7;
    const int loc    = id >> 3;          // 0..255
    const int strip  = loc >> 5;         // 0..7
    const int within = loc & 31;
    const int bm = (xcd * 8 + (within >> 2)) * BM;   // 0..63 * 128
    const int bn = (strip * 4 + (within & 3)) * BN;  // 0..31 * 128

    // staging: thread t loads 16B; row = t>>2, swizzled chunk = (t&3)^((t>>3)&3)
    const int srow = t >> 2;                            // 0..63
    const int csw  = (((t & 3) ^ ((t >> 3) & 3))) * 8;  // swizzled col (u16 units)
    const u16* ga = A + (size_t)(bm + srow) * K + csw;
    const u16* gb = B + (size_t)(bn + srow) * K + csw;
    u16* la = &As[wave * 512];   // wave-uniform LDS dest (lane scatter HW-implicit)
    u16* lb = &Bs[wave * 512];

    const int wm = (wave >> 1) * 64;   // 2x2 waves -> 64x64 per wave
    const int wn = (wave & 1) * 64;

    // fragment-read swizzle key (lane-constant): chunk slot = quad ^ ((r16>>1)&3)
    const int xsw = (quad ^ ((r16 >> 1) & 3)) * 8;

    f32x4 acc[4][4];
#pragma unroll
    for (int i = 0; i < 4; i++)
#pragma unroll
        for (int j = 0; j < 4; j++) acc[i][j] = (f32x4)0.0f;

    for (int kt = 0; kt < K / BK; ++kt) {
        ld_lds16(ga, la);
        ld_lds16(ga + 64 * K, la + 2048);
        ld_lds16(gb, lb);
        ld_lds16(gb + 64 * K, lb + 2048);
        ga += BK;
        gb += BK;
        __syncthreads();   // drains vmcnt -> LDS tiles complete

        shortx8 af[4], bf[4];
#pragma unroll
        for (int i = 0; i < 4; i++)
            af[i] = *(const shortx8*)&As[(wm + i * 16 + r16) * BK + xsw];
#pragma unroll
        for (int j = 0; j < 4; j++)
            bf[j] = *(const shortx8*)&Bs[(wn + j * 16 + r16) * BK + xsw];

#pragma unroll
        for (int i = 0; i < 4; i++)
#pragma unroll
            for (int j = 0; j < 4; j++)
                acc[i][j] = __builtin_amdgcn_mfma_f32_16x16x32_bf16(
                    af[i], bf[j], acc[i][j], 0, 0, 0);
        __syncthreads();   // protect LDS before next stage
    }

    // epilogue: C/D layout col=lane&15, row=quad*4+reg  [verified m89]
    // non-temporal: C is never re-read; keep L2 for A/B tiles.
#pragma unroll
    for (int i = 0; i < 4; i++) {
#pragma unroll
        for (int j = 0; j < 4; j++) {
            const int row0 = bm + wm + i * 16 + quad * 4;
            const int col  = bn + wn + j * 16 + r16;
#pragma unroll
            for (int v = 0; v < 4; ++v)
                __builtin_nontemporal_store(acc[i][j][v],
                                            &C[(size_t)(row0 + v) * N + col]);
        }
    }
}

// ---------------- fallback (ws too small): fp32 tiled, dequant on the fly ----------------

__global__ __launch_bounds__(256) void fallback_gemm(const float* __restrict__ x,
                                                     const int* __restrict__ qi,
                                                     const float* __restrict__ sc,
                                                     float* __restrict__ y) {
    __shared__ float xs[16][16];
    __shared__ float wsm[16][17];
    const int tx = threadIdx.x, ty = threadIdx.y;
    const int m = blockIdx.y * 16 + ty;
    const int nrow = blockIdx.x * 16 + ty;   // W row loaded by this thread
    float acc = 0.f;
    for (int k0 = 0; k0 < 4096; k0 += 16) {
        xs[ty][tx] = x[(size_t)m * 4096 + k0 + tx];
        const size_t fi = (size_t)nrow * 4096 + k0 + tx;
        wsm[ty][tx] = NF4C[qi[fi]] * sc[fi >> 10];
        __syncthreads();
#pragma unroll
        for (int kk = 0; kk < 16; kk++) acc += xs[ty][kk] * wsm[tx][kk];
        __syncthreads();
    }
    y[(size_t)m * 4096 + blockIdx.x * 16 + tx] = acc;
}

// ---------------- launch ----------------

extern "C" void kernel_launch(void* const* d_in, const int* in_sizes, int n_in,
                              void* d_out, int out_size, void* d_ws, size_t ws_size,
                              hipStream_t stream) {
    const float* x  = (const float*)d_in[0];
    const int*   qi = (const int*)d_in[1];
    const float* sc = (const float*)d_in[2];
    float* y = (float*)d_out;

    const int M = 8192, N = 4096, K = 4096;
    const size_t xb_bytes = (size_t)M * K * 2;   // 64 MiB
    const size_t wb_bytes = (size_t)N * K * 2;   // 32 MiB

    if (ws_size >= xb_bytes + wb_bytes) {
        u16* xb = (u16*)d_ws;
        u16* wb = (u16*)((char*)d_ws + xb_bytes);
        cvt_x<<<(M * K) / (256 * 8), 256, 0, stream>>>(x, xb);
        deq_w<<<(N * K) / (256 * 8), 256, 0, stream>>>(qi, sc, wb);
        gemm_bt<<<(M / BM) * (N / BN), 256, 0, stream>>>(xb, wb, y);
    } else {
        dim3 block(16, 16);
        dim3 grid(N / 16, M / 16);
        fallback_gemm<<<grid, block, 0, stream>>>(x, qi, sc, y);
    }
}

// Round 4
// 521.613 us; speedup vs baseline: 1.2686x; 1.1863x over previous
//
#include <hip/hip_runtime.h>

typedef unsigned short u16;
typedef __attribute__((ext_vector_type(4))) float  f32x4;
typedef __attribute__((ext_vector_type(4))) int    i32x4;
typedef __attribute__((ext_vector_type(4))) unsigned u32x4;
typedef __attribute__((ext_vector_type(8))) short  shortx8;

__device__ __constant__ float NF4C[16] = {
    -1.0f, -0.6962f, -0.5251f, -0.3949f, -0.2844f, -0.1848f, -0.0911f, 0.0f,
     0.0796f, 0.1609f, 0.2461f, 0.3379f, 0.4407f, 0.5626f, 0.723f, 1.0f};

__device__ __forceinline__ unsigned f2bf(float f) {
    unsigned u = __float_as_uint(f);
    return (u + 0x7FFFu + ((u >> 16) & 1u)) >> 16;   // RNE
}

__device__ __forceinline__ void ld_lds16(const u16* g, u16* l) {
    __builtin_amdgcn_global_load_lds(
        (const __attribute__((address_space(1))) void*)g,
        (__attribute__((address_space(3))) void*)l,
        16, 0, 0);
}

// ---------------- preprocessing ----------------

__global__ __launch_bounds__(256) void cvt_x(const float* __restrict__ x,
                                             u16* __restrict__ xb) {
    const size_t i = ((size_t)blockIdx.x * 256 + threadIdx.x) * 8;
    f32x4 f0 = __builtin_nontemporal_load((const f32x4*)(x + i));      // read-once
    f32x4 f1 = __builtin_nontemporal_load((const f32x4*)(x + i + 4));
    u32x4 o;
    o[0] = f2bf(f0[0]) | (f2bf(f0[1]) << 16);
    o[1] = f2bf(f0[2]) | (f2bf(f0[3]) << 16);
    o[2] = f2bf(f1[0]) | (f2bf(f1[1]) << 16);
    o[3] = f2bf(f1[2]) | (f2bf(f1[3]) << 16);
    *(u32x4*)(xb + i) = o;   // cached: GEMM re-reads from L2/L3
}

__global__ __launch_bounds__(256) void deq_w(const int* __restrict__ qi,
                                             const float* __restrict__ sc,
                                             u16* __restrict__ wb) {
    const size_t i = ((size_t)blockIdx.x * 256 + threadIdx.x) * 8;
    const float s = sc[i >> 10];          // 8 consecutive elems share one 1024-block
    i32x4 q0 = __builtin_nontemporal_load((const i32x4*)(qi + i));     // read-once
    i32x4 q1 = __builtin_nontemporal_load((const i32x4*)(qi + i + 4));
    u32x4 o;
    o[0] = f2bf(NF4C[q0[0]] * s) | (f2bf(NF4C[q0[1]] * s) << 16);
    o[1] = f2bf(NF4C[q0[2]] * s) | (f2bf(NF4C[q0[3]] * s) << 16);
    o[2] = f2bf(NF4C[q1[0]] * s) | (f2bf(NF4C[q1[1]] * s) << 16);
    o[3] = f2bf(NF4C[q1[2]] * s) | (f2bf(NF4C[q1[3]] * s) << 16);
    *(u32x4*)(wb + i) = o;
}

// ---------------- main GEMM: 256x128 block tile, 128x64 wave tile ----------------
// A: [M,K] bf16 row-major (x), B: [N,K] bf16 row-major (W) -> C = A*B^T, fp32 [M,N]
//
// Rationale: LDS-read bytes/FLOP = (Wm+Wn)/(Wm*Wn). 64x64 wave tile made LDS the
// binding pipe (~500 cyc vs 270 cyc MFMA per block-iter). 128x64 wave tile:
// LDS 48KB/iter ~770 cyc < MFMA 1082 cyc -> MFMA-bound.
//
// Staging groups: 64 rows x 32 u16 = 2048 u16 per group (R3 bug: used 4096).
//
// XOR bank swizzle (verified 0-conflict in R2): LDS chunk slot (row,c) holds
// global chunk c ^ ((row>>1)&3); staging lane fetches (t&3)^((t>>3)&3);
// fragment reads use key (quad ^ ((r16>>1)&3)) -> 2 lanes/bank (free, m136).

#define BM 256
#define BN 128
#define BK 32

__global__ __launch_bounds__(256, 2) void gemm_bt(const u16* __restrict__ A,
                                                  const u16* __restrict__ B,
                                                  float* __restrict__ C) {
    constexpr int K = 4096, N = 4096;
    __shared__ __align__(16) u16 As[BM * BK];   // 16 KiB
    __shared__ __align__(16) u16 Bs[BN * BK];   //  8 KiB

    const int t    = threadIdx.x;
    const int wave = t >> 6;
    const int lane = t & 63;
    const int quad = lane >> 4;
    const int r16  = lane & 15;

    // XCD swizzle: id%8 = XCD; each XCD covers 4 bm-rows x 32 bn-cols, bn-fast.
    const int id  = blockIdx.x;        // 0..1023
    const int xcd = id & 7;
    const int loc = id >> 3;           // 0..127
    const int bm  = (xcd * 4 + (loc >> 5)) * BM;   // 0..31 * 256
    const int bn  = (loc & 31) * BN;               // 0..31 * 128

    // staging: thread t covers row (g*64 + t>>2), swizzled 16B chunk (t&3)^((t>>3)&3)
    const int srow = t >> 2;                            // 0..63
    const int csw  = (((t & 3) ^ ((t >> 3) & 3))) * 8;  // swizzled col (u16 units)
    const u16* ga = A + (size_t)(bm + srow) * K + csw;
    const u16* gb = B + (size_t)(bn + srow) * K + csw;
    u16* la = &As[wave * 512];   // wave-uniform LDS base (lane*16B scatter HW-implicit)
    u16* lb = &Bs[wave * 512];

    const int wm = (wave >> 1) * 128;   // wave tile 128(m) x 64(n)
    const int wn = (wave & 1) * 64;

    // fragment-read swizzle key (lane-constant)
    const int xsw = (quad ^ ((r16 >> 1) & 3)) * 8;

    f32x4 acc[8][4];
#pragma unroll
    for (int i = 0; i < 8; i++)
#pragma unroll
        for (int j = 0; j < 4; j++) acc[i][j] = (f32x4)0.0f;

    for (int kt = 0; kt < K / BK; ++kt) {
        // each 64-row group = 64*32 = 2048 u16 in LDS
        ld_lds16(ga,             la);
        ld_lds16(ga +  64 * K,   la + 2048);
        ld_lds16(ga + 128 * K,   la + 4096);
        ld_lds16(ga + 192 * K,   la + 6144);
        ld_lds16(gb,             lb);
        ld_lds16(gb +  64 * K,   lb + 2048);
        ga += BK;
        gb += BK;
        __syncthreads();   // drains vmcnt -> LDS tiles complete

        shortx8 af[8], bf[4];
#pragma unroll
        for (int i = 0; i < 8; i++)
            af[i] = *(const shortx8*)&As[(wm + i * 16 + r16) * BK + xsw];
#pragma unroll
        for (int j = 0; j < 4; j++)
            bf[j] = *(const shortx8*)&Bs[(wn + j * 16 + r16) * BK + xsw];

#pragma unroll
        for (int i = 0; i < 8; i++)
#pragma unroll
            for (int j = 0; j < 4; j++)
                acc[i][j] = __builtin_amdgcn_mfma_f32_16x16x32_bf16(
                    af[i], bf[j], acc[i][j], 0, 0, 0);
        __syncthreads();   // protect LDS before next stage
    }

    // epilogue: C/D layout col=lane&15, row=quad*4+reg  [verified m89]
    // plain stores (nt stores inflated WRITE_SIZE 134->181 MB in R2)
#pragma unroll
    for (int i = 0; i < 8; i++) {
        const int row0 = bm + wm + i * 16 + quad * 4;
#pragma unroll
        for (int j = 0; j < 4; j++) {
            const int col = bn + wn + j * 16 + r16;
            float* cp = &C[(size_t)row0 * N + col];
#pragma unroll
            for (int v = 0; v < 4; ++v)
                cp[(size_t)v * N] = acc[i][j][v];
        }
    }
}

// ---------------- fallback (ws too small): fp32 tiled, dequant on the fly ----------------

__global__ __launch_bounds__(256) void fallback_gemm(const float* __restrict__ x,
                                                     const int* __restrict__ qi,
                                                     const float* __restrict__ sc,
                                                     float* __restrict__ y) {
    __shared__ float xs[16][16];
    __shared__ float wsm[16][17];
    const int tx = threadIdx.x, ty = threadIdx.y;
    const int m = blockIdx.y * 16 + ty;
    const int nrow = blockIdx.x * 16 + ty;   // W row loaded by this thread
    float acc = 0.f;
    for (int k0 = 0; k0 < 4096; k0 += 16) {
        xs[ty][tx] = x[(size_t)m * 4096 + k0 + tx];
        const size_t fi = (size_t)nrow * 4096 + k0 + tx;
        wsm[ty][tx] = NF4C[qi[fi]] * sc[fi >> 10];
        __syncthreads();
#pragma unroll
        for (int kk = 0; kk < 16; kk++) acc += xs[ty][kk] * wsm[tx][kk];
        __syncthreads();
    }
    y[(size_t)m * 4096 + blockIdx.x * 16 + tx] = acc;
}

// ---------------- launch ----------------

extern "C" void kernel_launch(void* const* d_in, const int* in_sizes, int n_in,
                              void* d_out, int out_size, void* d_ws, size_t ws_size,
                              hipStream_t stream) {
    const float* x  = (const float*)d_in[0];
    const int*   qi = (const int*)d_in[1];
    const float* sc = (const float*)d_in[2];
    float* y = (float*)d_out;

    const int M = 8192, N = 4096, K = 4096;
    const size_t xb_bytes = (size_t)M * K * 2;   // 64 MiB
    const size_t wb_bytes = (size_t)N * K * 2;   // 32 MiB

    if (ws_size >= xb_bytes + wb_bytes) {
        u16* xb = (u16*)d_ws;
        u16* wb = (u16*)((char*)d_ws + xb_bytes);
        cvt_x<<<(M * K) / (256 * 8), 256, 0, stream>>>(x, xb);
        deq_w<<<(N * K) / (256 * 8), 256, 0, stream>>>(qi, sc, wb);
        gemm_bt<<<(M / BM) * (N / BN), 256, 0, stream>>>(xb, wb, y);
    } else {
        dim3 block(16, 16);
        dim3 grid(N / 16, M / 16);
        fallback_gemm<<<grid, block, 0, stream>>>(x, qi, sc, y);
    }
}